// Round 5
// baseline (165.650 us; speedup 1.0000x reference)
//
#include <hip/hip_runtime.h>
#include <cstdint>
#include <cstddef>

// VarianceAdaptor — R5: 2x2 wave decomposition in conv (halves LDS A-reads,
// which R4 analysis showed were the CU-wide bottleneck: 576 LDS cyc vs 232
// matrix cyc per K-step). B=64, S=512, T=2048, H=F=256, K=3, NBINS=256.

#define HH 256
#define SS 512
#define BB 64
#define TT 2048

typedef __bf16 bf16;
typedef __attribute__((ext_vector_type(8))) __bf16 bf16x8;
typedef __attribute__((ext_vector_type(4))) __bf16 bf16x4;
typedef __attribute__((ext_vector_type(4))) float f32x4;

static constexpr size_t WSZ  = (size_t)3 * HH * HH;   // elems per conv weight
static constexpr size_t H1SZ = (size_t)BB * SS * HH;  // elems per h1 buffer

// swizzled halfword index into a [rows][256] bf16 LDS tile (row stride 512B).
__device__ __forceinline__ int swz(int r, int c) { return (r * HH + c) ^ ((r & 7) << 3); }

// ---------------- bucket (searchsorted over jnp.linspace(-2,2,255) edges) ----
__device__ __forceinline__ float edge_val(int j) {
    const float step = 4.0f / 254.0f;
    if (j == 254) return 2.0f;
    return __fadd_rn(-2.0f, __fmul_rn((float)j, step));
}
__device__ __forceinline__ int bucket256(float v) {
    int lo = 0, hi = 255;
    while (lo < hi) {
        int mid = (lo + hi) >> 1;
        if (edge_val(mid) < v) lo = mid + 1; else hi = mid;
    }
    return lo;
}

// ------------- weight pack: w[k][c][f] f32 -> wp[k][fb][kcb][lane][8] bf16 ---
// B-frag for mfma_16x16x32: lane l holds B[col = fb*16 + (l&15)]
//                                  [c   = kcb*32 + (l>>4)*8 + j], j=0..7
__global__ void wt_pack(const float* __restrict__ w0, const float* __restrict__ w1,
                        const float* __restrict__ w2, const float* __restrict__ w3,
                        const float* __restrict__ w4, const float* __restrict__ w5,
                        bf16* __restrict__ wp) {
    const int cv = blockIdx.x / 3, k = blockIdx.x % 3;
    const float* wsel[6] = {w0, w1, w2, w3, w4, w5};
    const float* wk = wsel[cv] + (size_t)k * HH * HH;   // [c][f]
    bf16* o = wp + ((size_t)(cv * 3 + k)) * HH * HH;
    for (int fb = 0; fb < 16; ++fb) {
        #pragma unroll
        for (int h = 0; h < 2; ++h) {
            const int idx  = threadIdx.x + 256 * h;     // 0..511
            const int kcb  = idx >> 6, lane = idx & 63;
            const int f    = fb * 16 + (lane & 15);
            const int c0   = kcb * 32 + (lane >> 4) * 8;
            bf16x8 v;
            #pragma unroll
            for (int j = 0; j < 8; ++j) v[j] = (bf16)wk[(size_t)(c0 + j) * HH + f];
            *(bf16x8*)(o + (((size_t)fb * 8 + kcb) * 64 + lane) * 8) = v;
        }
    }
}

// ---------------- merged fused conv (3 predictors in one grid) ---------------
struct Args3 {
    const float* bias[3];
    const float* g[3];
    const float* be[3];
    const float* lw[3];
    const float* lb[3];
    float*       out[3];
};

// grid = 3*512; 256 threads = 4 waves arranged 2x2:
// wave (wr,wc) owns rows [32wr,32wr+32) x cols [128wc,128wc+128).
template <bool LIN>
__global__ __launch_bounds__(256, 3) void conv_all(
    const void* __restrict__ in,      // !LIN: x f32 ; LIN: h1 base bf16
    const float* __restrict__ tab,    // p_table (pred 2, !LIN)
    const float* __restrict__ tgt,    // pitch_target
    const bf16* __restrict__ wpk,     // packed weights, 6 convs
    Args3 args,
    bf16* __restrict__ h1out,         // !LIN output base
    const uint8_t* __restrict__ mask) // LIN only
{
    __shared__ alignas(16) bf16 tile[66 * HH];
    __shared__ float red_s[64][2], red_q[64][2];
    __shared__ float ln_m[64], ln_r[64];
    __shared__ int remb[66];

    const int tid    = threadIdx.x;
    const int pred   = blockIdx.x >> 9;
    const int within = blockIdx.x & 511;
    const int b      = within >> 3;
    const int s0     = (within & 7) * 64;
    const bool emb   = (!LIN) && (pred == 2);

    if (emb) {
        if (tid < 66) {
            int s = s0 - 1 + tid;
            remb[tid] = (s >= 0 && s < SS) ? bucket256(tgt[b * SS + s]) : 0;
        }
        __syncthreads();
    }

    if (!LIN) {
        const float* inb = (const float*)in + (size_t)b * SS * HH;
        for (int idx = tid; idx < 66 * 64; idx += 256) {
            const int r = idx >> 6, c4 = (idx & 63) << 2;
            const int s = s0 - 1 + r;
            float4 v = make_float4(0.f, 0.f, 0.f, 0.f);
            if (s >= 0 && s < SS) {
                v = *(const float4*)(inb + (size_t)s * HH + c4);
                if (emb) {
                    const float4 tv = *(const float4*)(tab + (size_t)remb[r] * HH + c4);
                    v.x += tv.x; v.y += tv.y; v.z += tv.z; v.w += tv.w;
                }
            }
            bf16x4 bv = {(bf16)v.x, (bf16)v.y, (bf16)v.z, (bf16)v.w};
            *(bf16x4*)&tile[swz(r, c4)] = bv;
        }
    } else {
        const bf16* inb = (const bf16*)in + (size_t)pred * H1SZ + (size_t)b * SS * HH;
        for (int idx = tid; idx < 66 * 32; idx += 256) {
            const int r = idx >> 5, c8 = (idx & 31) << 3;
            const int s = s0 - 1 + r;
            bf16x8 v = {};
            if (s >= 0 && s < SS) v = *(const bf16x8*)(inb + (size_t)s * HH + c8);
            *(bf16x8*)&tile[swz(r, c8)] = v;
        }
    }
    __syncthreads();

    const int lane = tid & 63;
    const int wv   = tid >> 6;
    const int wr   = wv >> 1;            // row half   (0/1)
    const int wc   = wv & 1;             // col half   (0/1)
    const int ln15 = lane & 15;
    const int g8   = (lane >> 4) << 3;

    const bf16* wt = wpk + (size_t)(pred * 2 + (LIN ? 1 : 0)) * WSZ;

    f32x4 acc[2][8];
    #pragma unroll
    for (int nf = 0; nf < 8; ++nf) {
        const float bv = args.bias[pred][wc * 128 + nf * 16 + ln15];
        #pragma unroll
        for (int mf = 0; mf < 2; ++mf) acc[mf][nf] = f32x4{bv, bv, bv, bv};
    }

    // flat 24-step K-loop: t -> k = t>>3, kcb = t&7
    #pragma unroll 2
    for (int t = 0; t < 24; ++t) {
        const int k = t >> 3, kcb = t & 7;
        const int kc = kcb << 5;
        bf16x8 a[2], bb[8];
        #pragma unroll
        for (int mf = 0; mf < 2; ++mf)
            a[mf] = *(const bf16x8*)&tile[swz(32 * wr + 16 * mf + ln15 + k, kc + g8)];
        const bf16* bp = wt + ((((size_t)k * 16 + wc * 8) * 8 + kcb) << 9) + (size_t)lane * 8;
        #pragma unroll
        for (int nf = 0; nf < 8; ++nf)
            bb[nf] = *(const bf16x8*)(bp + ((size_t)nf << 12));
        #pragma unroll
        for (int mf = 0; mf < 2; ++mf)
            #pragma unroll
            for (int nf = 0; nf < 8; ++nf)
                acc[mf][nf] = __builtin_amdgcn_mfma_f32_16x16x32_bf16(
                    a[mf], bb[nf], acc[mf][nf], 0, 0, 0);
    }

    // ReLU
    #pragma unroll
    for (int mf = 0; mf < 2; ++mf)
        #pragma unroll
        for (int nf = 0; nf < 8; ++nf)
            #pragma unroll
            for (int i = 0; i < 4; ++i)
                acc[mf][nf][i] = fmaxf(acc[mf][nf][i], 0.f);

    // LN partials: this wave covers 128 of the row's 256 cols.
    #pragma unroll
    for (int mf = 0; mf < 2; ++mf) {
        #pragma unroll
        for (int i = 0; i < 4; ++i) {
            float s = 0.f, q = 0.f;
            #pragma unroll
            for (int nf = 0; nf < 8; ++nf) {
                s += acc[mf][nf][i];
                q += acc[mf][nf][i] * acc[mf][nf][i];
            }
            #pragma unroll
            for (int off = 1; off < 16; off <<= 1) {
                s += __shfl_xor(s, off);
                q += __shfl_xor(q, off);
            }
            if (ln15 == 0) {
                const int row = 32 * wr + 16 * mf + (lane >> 4) * 4 + i;
                red_s[row][wc] = s;
                red_q[row][wc] = q;
            }
        }
    }
    __syncthreads();
    if (tid < 64) {
        const float s = red_s[tid][0] + red_s[tid][1];
        const float q = red_q[tid][0] + red_q[tid][1];
        const float mean = s * (1.f / 256.f);
        const float var  = q * (1.f / 256.f) - mean * mean;
        ln_m[tid] = mean;
        ln_r[tid] = rsqrtf(var + 1e-5f);
    }
    __syncthreads();

    float gv[8], bev[8];
    #pragma unroll
    for (int nf = 0; nf < 8; ++nf) {
        const int col = wc * 128 + nf * 16 + ln15;
        gv[nf]  = args.g[pred][col];
        bev[nf] = args.be[pred][col];
    }

    if (!LIN) {
        bf16* ob = h1out + (size_t)pred * H1SZ + ((size_t)(b * SS + s0)) * HH;
        #pragma unroll
        for (int mf = 0; mf < 2; ++mf) {
            #pragma unroll
            for (int i = 0; i < 4; ++i) {
                const int row = 32 * wr + 16 * mf + (lane >> 4) * 4 + i;
                const float mean = ln_m[row], rs = ln_r[row];
                #pragma unroll
                for (int nf = 0; nf < 8; ++nf) {
                    const float o = (acc[mf][nf][i] - mean) * rs * gv[nf] + bev[nf];
                    ob[(size_t)row * HH + wc * 128 + nf * 16 + ln15] = (bf16)o;
                }
            }
        }
    } else {
        float lwv[8];
        #pragma unroll
        for (int nf = 0; nf < 8; ++nf) lwv[nf] = args.lw[pred][wc * 128 + nf * 16 + ln15];
        const float lb0 = args.lb[pred][0];
        #pragma unroll
        for (int mf = 0; mf < 2; ++mf) {
            #pragma unroll
            for (int i = 0; i < 4; ++i) {
                const int row = 32 * wr + 16 * mf + (lane >> 4) * 4 + i;
                const float mean = ln_m[row], rs = ln_r[row];
                float t = 0.f;
                #pragma unroll
                for (int nf = 0; nf < 8; ++nf)
                    t += ((acc[mf][nf][i] - mean) * rs * gv[nf] + bev[nf]) * lwv[nf];
                #pragma unroll
                for (int off = 1; off < 16; off <<= 1) t += __shfl_xor(t, off);
                if (ln15 == 0) red_s[row][wc] = t;
            }
        }
        __syncthreads();
        if (tid < 64) {
            const int gr = b * SS + s0 + tid;
            const float dv = red_s[tid][0] + red_s[tid][1] + lb0;
            args.out[pred][gr] = mask[gr] ? 0.f : dv;
        }
    }
}

// ------- duration cumsum + d_rounded + mel_len + scatter expansion index -----
__global__ void dur_kernel(const int* __restrict__ dur, int* __restrict__ idxb,
                           int* __restrict__ mli,
                           float* __restrict__ drnd, float* __restrict__ mlen) {
    __shared__ int sb[SS];
    const int b = blockIdx.x, t = threadIdx.x;
    const int v = dur[b * SS + t];
    drnd[b * SS + t] = (float)v;
    sb[t] = v;
    __syncthreads();
    for (int off = 1; off < SS; off <<= 1) {
        const int add = (t >= off) ? sb[t - off] : 0;
        __syncthreads();
        sb[t] += add;
        __syncthreads();
    }
    const int hi = sb[t];
    const int lo = hi - v;
    for (int j = lo; j < hi; ++j) idxb[b * TT + j] = t;   // disjoint ranges
    if (t == SS - 1) { mlen[b] = (float)hi; mli[b] = hi; }
}

// ---------------- length regulator (precomputed idx, grid-stride) ------------
__global__ __launch_bounds__(256) void gather_kernel(
    const float* __restrict__ x,
    const float* __restrict__ ptab, const float* __restrict__ pt,
    const float* __restrict__ etab, const float* __restrict__ et,
    const int* __restrict__ idxb, const int* __restrict__ mli,
    float* __restrict__ mel)
{
    const int lane = threadIdx.x & 63;
    for (int row = blockIdx.x * 4 + (threadIdx.x >> 6); row < BB * TT; row += 4096 * 4) {
        const int b = row >> 11;
        const int t = row & (TT - 1);
        float4 v = make_float4(0.f, 0.f, 0.f, 0.f);
        if (t < mli[b]) {
            const int idx = idxb[row];
            const size_t src = ((size_t)b * SS + idx) * HH + lane * 4;
            v = *(const float4*)(x + src);
            const int pb = bucket256(pt[b * SS + idx]);
            const int eb = bucket256(et[b * SS + idx]);
            const float4 pv = *(const float4*)(ptab + (size_t)pb * HH + lane * 4);
            const float4 ev = *(const float4*)(etab + (size_t)eb * HH + lane * 4);
            v.x += pv.x + ev.x; v.y += pv.y + ev.y; v.z += pv.z + ev.z; v.w += pv.w + ev.w;
        }
        *(float4*)(mel + (size_t)row * HH + lane * 4) = v;
    }
}

// ---------------- launch -----------------------------------------------------
extern "C" void kernel_launch(void* const* d_in, const int* in_sizes, int n_in,
                              void* d_out, int out_size, void* d_ws, size_t ws_size,
                              hipStream_t stream) {
    (void)in_sizes; (void)n_in; (void)out_size; (void)ws_size;

    const float*   x      = (const float*)d_in[0];
    const float*   pitch  = (const float*)d_in[1];
    const float*   energy = (const float*)d_in[2];
    const uint8_t* mask   = (const uint8_t*)d_in[3];
    const int*     dur    = (const int*)d_in[4];
    const float*   ptab   = (const float*)d_in[36];
    const float*   etab   = (const float*)d_in[37];

    float* out = (float*)d_out;
    const size_t N_MEL = (size_t)BB * TT * HH;
    float* out_p  = out + N_MEL;
    float* out_e  = out_p + (size_t)BB * SS;
    float* out_ld = out_e + (size_t)BB * SS;
    float* out_dr = out_ld + (size_t)BB * SS;
    float* out_ml = out_dr + (size_t)BB * SS;

    // ws: packed weights (2.36 MB) | idxb (B*T int, 512 KB) | mli (64 int)
    bf16* wpk  = (bf16*)d_ws;
    int*  idxb = (int*)(wpk + 6 * WSZ);
    int*  mli  = idxb + (size_t)BB * TT;

    // h1 (3 x 16MB bf16) lives in the mel output region — dead by the time
    // gather_kernel (the last kernel) overwrites all of mel.
    bf16* h1 = (bf16*)out;

    wt_pack<<<18, 256, 0, stream>>>(
        (const float*)d_in[6],  (const float*)d_in[10],
        (const float*)d_in[16], (const float*)d_in[20],
        (const float*)d_in[26], (const float*)d_in[30],
        wpk);
    dur_kernel<<<BB, SS, 0, stream>>>(dur, idxb, mli, out_dr, out_ml);

    Args3 a1 = {
        {(const float*)d_in[7],  (const float*)d_in[17], (const float*)d_in[27]},
        {(const float*)d_in[8],  (const float*)d_in[18], (const float*)d_in[28]},
        {(const float*)d_in[9],  (const float*)d_in[19], (const float*)d_in[29]},
        {nullptr, nullptr, nullptr}, {nullptr, nullptr, nullptr},
        {nullptr, nullptr, nullptr}
    };
    Args3 a2 = {
        {(const float*)d_in[11], (const float*)d_in[21], (const float*)d_in[31]},
        {(const float*)d_in[12], (const float*)d_in[22], (const float*)d_in[32]},
        {(const float*)d_in[13], (const float*)d_in[23], (const float*)d_in[33]},
        {(const float*)d_in[14], (const float*)d_in[24], (const float*)d_in[34]},
        {(const float*)d_in[15], (const float*)d_in[25], (const float*)d_in[35]},
        {out_ld, out_p, out_e}
    };

    conv_all<false><<<3 * 512, 256, 0, stream>>>(x, ptab, pitch, wpk, a1, h1, nullptr);
    conv_all<true ><<<3 * 512, 256, 0, stream>>>(h1, nullptr, nullptr, wpk, a2, nullptr, mask);

    gather_kernel<<<4096, 256, 0, stream>>>(x, ptab, pitch, etab, energy, idxb, mli, out);
}